// Round 1
// baseline (173.809 us; speedup 1.0000x reference)
//
#include <hip/hip_runtime.h>
#include <math.h>

#define NX 2048
#define NV 1024
static constexpr float DXf   = 1.0f / 2048.0f;       // 4.8828125e-4
static constexpr float DVf   = 12.0f / 1024.0f;      // 0.01171875
static constexpr float DTf   = 0.001f;
static constexpr float INV_DX = 2048.0f;
static constexpr float INV_DV = 1024.0f / 12.0f;     // 85.3333...

__device__ __forceinline__ float minmod_f(float a, float b) {
    return (a * b > 0.0f) ? (a > 0.0f ? fminf(a, b) : fmaxf(a, b)) : 0.0f;
}

// rho[i] = DV * (sum_j fi[i,j] - sum_j fe[i,j])
__global__ __launch_bounds__(256) void moments_kernel(const float* __restrict__ fe,
                                                      const float* __restrict__ fi,
                                                      float* __restrict__ rho) {
    int i = blockIdx.x;
    int t = threadIdx.x;
    const float* re = fe + (size_t)i * NV;
    const float* ri = fi + (size_t)i * NV;
    float se = 0.0f, si = 0.0f;
    for (int j = t; j < NV; j += 256) { se += re[j]; si += ri[j]; }
    __shared__ float s1[256], s2[256];
    s1[t] = se; s2[t] = si;
    __syncthreads();
    for (int off = 128; off > 0; off >>= 1) {
        if (t < off) { s1[t] += s1[t + off]; s2[t] += s2[t + off]; }
        __syncthreads();
    }
    if (t == 0) rho[i] = DVf * (s2[0] - s1[0]);
}

// E = cumsum(rho)*DX; E -= mean(E).  Single block, 1024 threads, 2 elems/thread.
__global__ __launch_bounds__(1024) void poisson_kernel(const float* __restrict__ rho,
                                                       float* __restrict__ E) {
    __shared__ float p[1024];
    __shared__ float red[1024];
    int t = threadIdx.x;
    float r0 = rho[2 * t], r1 = rho[2 * t + 1];
    p[t] = r0 + r1;
    __syncthreads();
    // inclusive Hillis-Steele scan over 1024 pair sums
    for (int off = 1; off < 1024; off <<= 1) {
        float v = p[t];
        float add = (t >= off) ? p[t - off] : 0.0f;
        __syncthreads();
        p[t] = v + add;
        __syncthreads();
    }
    float Pexcl = (t > 0) ? p[t - 1] : 0.0f;
    float S0 = Pexcl + r0;     // inclusive prefix at 2t
    float S1 = p[t];           // inclusive prefix at 2t+1
    red[t] = S0 + S1;
    __syncthreads();
    for (int off = 512; off > 0; off >>= 1) {
        if (t < off) red[t] += red[t + off];
        __syncthreads();
    }
    float meanS = red[0] * (1.0f / (float)NX);
    E[2 * t]     = DXf * (S0 - meanS);
    E[2 * t + 1] = DXf * (S1 - meanS);
}

// out = c0*h + cg*g + cr * rhs(g)   (rhs = -v df/dx - Ec df/dv, MUSCL minmod upwind)
__global__ __launch_bounds__(256) void stage_kernel(const float* __restrict__ h,
                                                    const float* __restrict__ g,
                                                    const float* __restrict__ E,
                                                    float zoa, float c0, float cg, float cr,
                                                    float* __restrict__ out) {
    int j = blockIdx.x * 256 + threadIdx.x;
    int i = blockIdx.y;
    int idx = i * NV + j;
    int im1 = (((i - 1) & (NX - 1)) * NV) + j;
    int im2 = (((i - 2) & (NX - 1)) * NV) + j;
    int ip1 = (((i + 1) & (NX - 1)) * NV) + j;
    int ip2 = (((i + 2) & (NX - 1)) * NV) + j;

    float f0  = g[idx];
    float fm1 = g[im1], fm2 = g[im2], fp1 = g[ip1], fp2 = g[ip2];

    // x-direction (periodic), upwind by sign of v_j
    float v = DVf * ((float)j + 0.5f) - 6.0f;
    float dm1 = fm1 - fm2, d0 = f0 - fm1, dp1 = fp1 - f0, dp2 = fp2 - fp1;
    float sm1 = minmod_f(dm1, d0);
    float s0  = minmod_f(d0, dp1);
    float sp1 = minmod_f(dp1, dp2);
    float PhiM, PhiP;
    if (v > 0.0f) {
        PhiM = (fm1 + 0.5f * sm1) * v;
        PhiP = (f0  + 0.5f * s0 ) * v;
    } else {
        PhiM = (f0  - 0.5f * s0 ) * v;
        PhiP = (fp1 - 0.5f * sp1) * v;
    }
    float vdfdx = (PhiP - PhiM) * INV_DX;

    // v-direction (zero ghost cells), upwind by sign of Ec_i
    float gm1 = (j >= 1)      ? g[idx - 1] : 0.0f;
    float gm2 = (j >= 2)      ? g[idx - 2] : 0.0f;
    float gp1 = (j <= NV - 2) ? g[idx + 1] : 0.0f;
    float gp2 = (j <= NV - 3) ? g[idx + 2] : 0.0f;
    float Ec = zoa * E[i];
    float em1 = gm1 - gm2, e0 = f0 - gm1, ep1 = gp1 - f0, ep2 = gp2 - gp1;
    float tm1 = minmod_f(em1, e0);
    float t0  = minmod_f(e0, ep1);
    float tp1 = minmod_f(ep1, ep2);
    float GM, GP;
    if (Ec > 0.0f) {
        GM = (gm1 + 0.5f * tm1) * Ec;
        GP = (f0  + 0.5f * t0 ) * Ec;
    } else {
        GM = (f0  - 0.5f * t0 ) * Ec;
        GP = (gp1 - 0.5f * tp1) * Ec;
    }
    float Edfdv = (GP - GM) * INV_DV;

    float r = -vdfdx - Edfdv;
    out[idx] = c0 * h[idx] + cg * f0 + cr * r;
}

// In-place tridiagonal solve per (species, row) via parallel cyclic reduction.
// f layout: [2][NX][NV]; block = (row), grid = (NX, 2)
__global__ __launch_bounds__(1024) void collide_kernel(float* __restrict__ f) {
    int i  = blockIdx.x;
    int sp = blockIdx.y;
    float lam = (sp == 0) ? 1.0f : 0.1f;
    float* row = f + ((size_t)sp * NX + i) * NV;
    int j = threadIdx.x;

    const float Tdv2   = 1.0f / (DVf * DVf);   // T_LBO / DV^2, T=1
    const float inv2dv = 0.5f / DVf;

    float xi = DXf * ((float)i + 0.5f) - 0.5f;
    float nu = 1.0f / (1.0f + 0.5f * (expf(60.0f * xi - 20.0f) + expf(-60.0f * xi - 20.0f)));
    float k = DTf * nu;

    float vjm1 = DVf * ((float)(j - 1) + 0.5f) - 6.0f;
    float vjp1 = DVf * ((float)(j + 1) + 0.5f) - 6.0f;
    float dl = (j == 0)      ? 0.0f : lam * (Tdv2 - vjm1 * inv2dv);
    float du = (j == NV - 1) ? 0.0f : lam * (Tdv2 + vjp1 * inv2dv);
    float dd = -2.0f * lam * Tdv2;

    float a = -k * dl;
    float b = 1.0f - k * dd;
    float c = -k * du;
    float d = row[j];

    __shared__ float sa[NV], sb[NV], sc[NV], sd[NV];
    sa[j] = a; sb[j] = b; sc[j] = c; sd[j] = d;
    __syncthreads();

    for (int s = 1; s < NV; s <<= 1) {
        float am, bm, cm, dm, ap, bp, cp, dp;
        int jm = j - s, jp = j + s;
        if (jm >= 0) { am = sa[jm]; bm = sb[jm]; cm = sc[jm]; dm = sd[jm]; }
        else         { am = 0.0f;   bm = 1.0f;   cm = 0.0f;   dm = 0.0f;   }
        if (jp < NV) { ap = sa[jp]; bp = sb[jp]; cp = sc[jp]; dp = sd[jp]; }
        else         { ap = 0.0f;   bp = 1.0f;   cp = 0.0f;   dp = 0.0f;   }
        float alpha = -a / bm;
        float gamma = -c / bp;
        float na = alpha * am;
        float nb = b + alpha * cm + gamma * ap;
        float nc = gamma * cp;
        float nd = d + alpha * dm + gamma * dp;
        __syncthreads();
        sa[j] = na; sb[j] = nb; sc[j] = nc; sd[j] = nd;
        a = na; b = nb; c = nc; d = nd;
        __syncthreads();
    }
    row[j] = d / b;
}

extern "C" void kernel_launch(void* const* d_in, const int* in_sizes, int n_in,
                              void* d_out, int out_size, void* d_ws, size_t ws_size,
                              hipStream_t stream) {
    const float* fe = (const float*)d_in[0];
    const float* fi = (const float*)d_in[1];
    float* out = (float*)d_out;
    const size_t P = (size_t)NX * NV;

    float* fe1  = (float*)d_ws;
    float* fi1  = fe1 + P;
    float* rho  = fi1 + P;
    float* E    = rho + NX;
    float* rho1 = E + NX;
    float* E1   = rho1 + NX;

    dim3 sgrid(NV / 256, NX);
    const float ZOA_E = -1.0f;
    const float ZOA_I = 1.0f / 1836.0f;

    // ---- RK stage 1: f1 = f + dt * rhs(f) ----
    moments_kernel<<<NX, 256, 0, stream>>>(fe, fi, rho);
    poisson_kernel<<<1, 1024, 0, stream>>>(rho, E);
    stage_kernel<<<sgrid, 256, 0, stream>>>(fe, fe, E, ZOA_E, 0.0f, 1.0f, DTf, fe1);
    stage_kernel<<<sgrid, 256, 0, stream>>>(fi, fi, E, ZOA_I, 0.0f, 1.0f, DTf, fi1);

    // ---- RK stage 2: f2 = 0.5*f + 0.5*f1 + 0.5*dt*rhs(f1) ----
    moments_kernel<<<NX, 256, 0, stream>>>(fe1, fi1, rho1);
    poisson_kernel<<<1, 1024, 0, stream>>>(rho1, E1);
    stage_kernel<<<sgrid, 256, 0, stream>>>(fe, fe1, E1, ZOA_E, 0.5f, 0.5f, 0.5f * DTf, out);
    stage_kernel<<<sgrid, 256, 0, stream>>>(fi, fi1, E1, ZOA_I, 0.5f, 0.5f, 0.5f * DTf, out + P);

    // ---- implicit LBO collision, in-place on out ----
    dim3 cgrid(NX, 2);
    collide_kernel<<<cgrid, 1024, 0, stream>>>(out);
}

// Round 2
// 138.753 us; speedup vs baseline: 1.2526x; 1.2526x over previous
//
#include <hip/hip_runtime.h>
#include <math.h>

#define NX 2048
#define NV 1024
static constexpr float DXf   = 1.0f / 2048.0f;       // 4.8828125e-4
static constexpr float DVf   = 12.0f / 1024.0f;      // 0.01171875
static constexpr float DTf   = 0.001f;
static constexpr float INV_DX = 2048.0f;
static constexpr float INV_DV = 1024.0f / 12.0f;     // 85.3333...

__device__ __forceinline__ float minmod_f(float a, float b) {
    return (a * b > 0.0f) ? (a > 0.0f ? fminf(a, b) : fmaxf(a, b)) : 0.0f;
}

// fast reciprocal: v_rcp_f32 + 1 Newton step (~2e-7 rel err; system is diag-dominant)
__device__ __forceinline__ float frcp(float x) {
    float r = __builtin_amdgcn_rcpf(x);
    return r * (2.0f - x * r);
}

// rho[i] = DV * (sum_j fi[i,j] - sum_j fe[i,j])
__global__ __launch_bounds__(256) void moments_kernel(const float* __restrict__ fe,
                                                      const float* __restrict__ fi,
                                                      float* __restrict__ rho) {
    int i = blockIdx.x;
    int t = threadIdx.x;
    const float* re = fe + (size_t)i * NV;
    const float* ri = fi + (size_t)i * NV;
    float se = 0.0f, si = 0.0f;
    for (int j = t; j < NV; j += 256) { se += re[j]; si += ri[j]; }
    __shared__ float s1[256], s2[256];
    s1[t] = se; s2[t] = si;
    __syncthreads();
    for (int off = 128; off > 0; off >>= 1) {
        if (t < off) { s1[t] += s1[t + off]; s2[t] += s2[t + off]; }
        __syncthreads();
    }
    if (t == 0) rho[i] = DVf * (s2[0] - s1[0]);
}

// E = cumsum(rho)*DX; E -= mean(E).  Single block, 1024 threads, 2 elems/thread.
__global__ __launch_bounds__(1024) void poisson_kernel(const float* __restrict__ rho,
                                                       float* __restrict__ E) {
    __shared__ float p[1024];
    __shared__ float red[1024];
    int t = threadIdx.x;
    float r0 = rho[2 * t], r1 = rho[2 * t + 1];
    p[t] = r0 + r1;
    __syncthreads();
    for (int off = 1; off < 1024; off <<= 1) {
        float v = p[t];
        float add = (t >= off) ? p[t - off] : 0.0f;
        __syncthreads();
        p[t] = v + add;
        __syncthreads();
    }
    float Pexcl = (t > 0) ? p[t - 1] : 0.0f;
    float S0 = Pexcl + r0;
    float S1 = p[t];
    red[t] = S0 + S1;
    __syncthreads();
    for (int off = 512; off > 0; off >>= 1) {
        if (t < off) red[t] += red[t + off];
        __syncthreads();
    }
    float meanS = red[0] * (1.0f / (float)NX);
    E[2 * t]     = DXf * (S0 - meanS);
    E[2 * t + 1] = DXf * (S1 - meanS);
}

// out = c0*h + cg*g + cr * rhs(g), both species via blockIdx.z
__global__ __launch_bounds__(256) void stage_kernel(const float* __restrict__ he,
                                                    const float* __restrict__ hi,
                                                    const float* __restrict__ ge,
                                                    const float* __restrict__ gi,
                                                    const float* __restrict__ E,
                                                    float c0, float cg, float cr,
                                                    float* __restrict__ oute,
                                                    float* __restrict__ outi) {
    int sp = blockIdx.z;
    const float* h = sp ? hi : he;
    const float* g = sp ? gi : ge;
    float* out = sp ? outi : oute;
    float zoa = sp ? (1.0f / 1836.0f) : -1.0f;

    int j = blockIdx.x * 256 + threadIdx.x;
    int i = blockIdx.y;
    int idx = i * NV + j;
    int im1 = (((i - 1) & (NX - 1)) * NV) + j;
    int im2 = (((i - 2) & (NX - 1)) * NV) + j;
    int ip1 = (((i + 1) & (NX - 1)) * NV) + j;
    int ip2 = (((i + 2) & (NX - 1)) * NV) + j;

    float f0  = g[idx];
    float fm1 = g[im1], fm2 = g[im2], fp1 = g[ip1], fp2 = g[ip2];

    float v = DVf * ((float)j + 0.5f) - 6.0f;
    float dm1 = fm1 - fm2, d0 = f0 - fm1, dp1 = fp1 - f0, dp2 = fp2 - fp1;
    float sm1 = minmod_f(dm1, d0);
    float s0  = minmod_f(d0, dp1);
    float sp1 = minmod_f(dp1, dp2);
    float PhiM, PhiP;
    if (v > 0.0f) {
        PhiM = (fm1 + 0.5f * sm1) * v;
        PhiP = (f0  + 0.5f * s0 ) * v;
    } else {
        PhiM = (f0  - 0.5f * s0 ) * v;
        PhiP = (fp1 - 0.5f * sp1) * v;
    }
    float vdfdx = (PhiP - PhiM) * INV_DX;

    float gm1 = (j >= 1)      ? g[idx - 1] : 0.0f;
    float gm2 = (j >= 2)      ? g[idx - 2] : 0.0f;
    float gp1 = (j <= NV - 2) ? g[idx + 1] : 0.0f;
    float gp2 = (j <= NV - 3) ? g[idx + 2] : 0.0f;
    float Ec = zoa * E[i];
    float em1 = gm1 - gm2, e0 = f0 - gm1, ep1 = gp1 - f0, ep2 = gp2 - gp1;
    float tm1 = minmod_f(em1, e0);
    float t0  = minmod_f(e0, ep1);
    float tp1 = minmod_f(ep1, ep2);
    float GM, GP;
    if (Ec > 0.0f) {
        GM = (gm1 + 0.5f * tm1) * Ec;
        GP = (f0  + 0.5f * t0 ) * Ec;
    } else {
        GM = (f0  - 0.5f * t0 ) * Ec;
        GP = (gp1 - 0.5f * tp1) * Ec;
    }
    float Edfdv = (GP - GM) * INV_DV;

    float r = -vdfdx - Edfdv;
    out[idx] = c0 * h[idx] + cg * f0 + cr * r;
}

// Wave-per-row hybrid Thomas/SPIKE tridiagonal solve. 64 lanes x 16 elems.
// Per-lane register elimination -> x_r = D_r - A_r*z_left - C_r*y_right;
// lane 0 solves the 128-unknown interface chain serially; lanes reconstruct.
// f layout: [2][NX][NV]; block = 256 (4 waves = 4 rows); grid = 1024 blocks.
__global__ __launch_bounds__(256) void collide_kernel(float* __restrict__ f) {
    const float Tdv2   = 1.0f / (DVf * DVf);
    const float inv2dv = 0.5f / DVf;

    int lane = threadIdx.x & 63;
    int wave = threadIdx.x >> 6;
    int gr = blockIdx.x * 4 + wave;       // 0..4095
    int sp = gr >> 11;
    int i  = gr & (NX - 1);
    float lam = sp ? 0.1f : 1.0f;
    float* row = f + (size_t)gr * NV;

    float xi = DXf * ((float)i + 0.5f) - 0.5f;
    float nu = 1.0f / (1.0f + 0.5f * (expf(60.0f * xi - 20.0f) + expf(-60.0f * xi - 20.0f)));
    float K = DTf * nu * lam;             // dt * nu_i * lam
    float b = 1.0f + 2.0f * K * Tdv2;     // diagonal (constant along j)

    int j0 = lane * 16;
    float d[16];
    {
        float4 q0 = *(const float4*)(row + j0);
        float4 q1 = *(const float4*)(row + j0 + 4);
        float4 q2 = *(const float4*)(row + j0 + 8);
        float4 q3 = *(const float4*)(row + j0 + 12);
        d[0]=q0.x;  d[1]=q0.y;  d[2]=q0.z;  d[3]=q0.w;
        d[4]=q1.x;  d[5]=q1.y;  d[6]=q1.z;  d[7]=q1.w;
        d[8]=q2.x;  d[9]=q2.y;  d[10]=q2.z; d[11]=q2.w;
        d[12]=q3.x; d[13]=q3.y; d[14]=q3.z; d[15]=q3.w;
    }

    // forward elimination (normalized): x_r = Dv_r - Av_r*x_left - Cv_r*x_{r+1}
    float Dv[16], Av[16], Cv[16];
    #pragma unroll
    for (int r = 0; r < 16; ++r) {
        int j = j0 + r;
        float a = (j == 0)      ? 0.0f : -K * (Tdv2 - (DVf * ((float)j - 0.5f) - 6.0f) * inv2dv);
        float c = (j == NV - 1) ? 0.0f : -K * (Tdv2 + (DVf * ((float)j + 1.5f) - 6.0f) * inv2dv);
        if (r == 0) {
            float e = frcp(b);
            Dv[0] = e * d[0];
            Av[0] = e * a;
            Cv[0] = e * c;
        } else {
            float e = frcp(b - a * Cv[r - 1]);
            Dv[r] = e * (d[r] - a * Dv[r - 1]);
            Av[r] = -e * a * Av[r - 1];
            Cv[r] = e * c;
        }
    }
    // backward: x_r = Dv_r - Av_r*x_left - Cv_r*x_right (in-place transform)
    #pragma unroll
    for (int r = 14; r >= 0; --r) {
        Dv[r] = Dv[r] - Cv[r] * Dv[r + 1];
        Av[r] = Av[r] - Cv[r] * Av[r + 1];
        Cv[r] = -Cv[r] * Cv[r + 1];
    }

    __shared__ float ifc[4][64][6];
    ifc[wave][lane][0] = Av[0];
    ifc[wave][lane][1] = Cv[0];
    ifc[wave][lane][2] = Dv[0];
    ifc[wave][lane][3] = Av[15];
    ifc[wave][lane][4] = Cv[15];
    ifc[wave][lane][5] = Dv[15];
    __syncthreads();

    if (lane == 0) {
        // forward over interface chain: z_{t-1} = g2p - qp*y_t
        float qp = 0.0f, g2p = 0.0f;
        for (int t = 0; t < 64; ++t) {
            float A0 = ifc[wave][t][0], C0 = ifc[wave][t][1], D0 = ifc[wave][t][2];
            float A1 = ifc[wave][t][3], C1 = ifc[wave][t][4], D1 = ifc[wave][t][5];
            float e  = frcp(1.0f - A0 * qp);
            float p  = e * C0;
            float g1 = e * (D0 - A0 * g2p);
            float q  = A1 * qp * p + C1;
            float g2 = D1 - A1 * (g2p - qp * g1);
            ifc[wave][t][0] = p;
            ifc[wave][t][1] = q;
            ifc[wave][t][2] = g1;
            ifc[wave][t][3] = g2;
            qp = q; g2p = g2;
        }
        // backward: y_t = g1 - p*y_{t+1}, z_t = g2 - q*y_{t+1}
        float yn = 0.0f;
        for (int t = 63; t >= 0; --t) {
            float p  = ifc[wave][t][0], q  = ifc[wave][t][1];
            float g1 = ifc[wave][t][2], g2 = ifc[wave][t][3];
            float y = g1 - p * yn;
            float z = g2 - q * yn;
            ifc[wave][t][4] = y;
            ifc[wave][t][5] = z;
            yn = y;
        }
    }
    __syncthreads();

    float zl = (lane == 0)  ? 0.0f : ifc[wave][lane - 1][5];
    float yr = (lane == 63) ? 0.0f : ifc[wave][lane + 1][4];

    float4 o0, o1, o2, o3;
    o0.x = Dv[0]  - Av[0]  * zl - Cv[0]  * yr;
    o0.y = Dv[1]  - Av[1]  * zl - Cv[1]  * yr;
    o0.z = Dv[2]  - Av[2]  * zl - Cv[2]  * yr;
    o0.w = Dv[3]  - Av[3]  * zl - Cv[3]  * yr;
    o1.x = Dv[4]  - Av[4]  * zl - Cv[4]  * yr;
    o1.y = Dv[5]  - Av[5]  * zl - Cv[5]  * yr;
    o1.z = Dv[6]  - Av[6]  * zl - Cv[6]  * yr;
    o1.w = Dv[7]  - Av[7]  * zl - Cv[7]  * yr;
    o2.x = Dv[8]  - Av[8]  * zl - Cv[8]  * yr;
    o2.y = Dv[9]  - Av[9]  * zl - Cv[9]  * yr;
    o2.z = Dv[10] - Av[10] * zl - Cv[10] * yr;
    o2.w = Dv[11] - Av[11] * zl - Cv[11] * yr;
    o3.x = Dv[12] - Av[12] * zl - Cv[12] * yr;
    o3.y = Dv[13] - Av[13] * zl - Cv[13] * yr;
    o3.z = Dv[14] - Av[14] * zl - Cv[14] * yr;
    o3.w = Dv[15] - Av[15] * zl - Cv[15] * yr;
    *(float4*)(row + j0)      = o0;
    *(float4*)(row + j0 + 4)  = o1;
    *(float4*)(row + j0 + 8)  = o2;
    *(float4*)(row + j0 + 12) = o3;
}

extern "C" void kernel_launch(void* const* d_in, const int* in_sizes, int n_in,
                              void* d_out, int out_size, void* d_ws, size_t ws_size,
                              hipStream_t stream) {
    const float* fe = (const float*)d_in[0];
    const float* fi = (const float*)d_in[1];
    float* out = (float*)d_out;
    const size_t P = (size_t)NX * NV;

    float* fe1  = (float*)d_ws;
    float* fi1  = fe1 + P;
    float* rho  = fi1 + P;
    float* E    = rho + NX;
    float* rho1 = E + NX;
    float* E1   = rho1 + NX;

    dim3 sgrid(NV / 256, NX, 2);

    // ---- RK stage 1: f1 = f + dt * rhs(f) ----
    moments_kernel<<<NX, 256, 0, stream>>>(fe, fi, rho);
    poisson_kernel<<<1, 1024, 0, stream>>>(rho, E);
    stage_kernel<<<sgrid, 256, 0, stream>>>(fe, fi, fe, fi, E, 0.0f, 1.0f, DTf, fe1, fi1);

    // ---- RK stage 2: f2 = 0.5*f + 0.5*f1 + 0.5*dt*rhs(f1) ----
    moments_kernel<<<NX, 256, 0, stream>>>(fe1, fi1, rho1);
    poisson_kernel<<<1, 1024, 0, stream>>>(rho1, E1);
    stage_kernel<<<sgrid, 256, 0, stream>>>(fe, fi, fe1, fi1, E1, 0.5f, 0.5f, 0.5f * DTf, out, out + P);

    // ---- implicit LBO collision, in-place on out (wave-per-row hybrid) ----
    collide_kernel<<<(2 * NX) / 4, 256, 0, stream>>>(out);
}